// Round 6
// baseline (366.326 us; speedup 1.0000x reference)
//
#include <hip/hip_runtime.h>
#include <math.h>

typedef unsigned int u32;
typedef unsigned long long u64;

#define N_ALL 159882
#define NC 4507
#define MROW 72
#define NEGINF_KEY 0x007FFFFFu
#define IMGF 800.0f
#define BBOX_CLIP_F 4.135166556742356f
#define EMIT_S 16

// NHWC scratch geometry (floats, per batch)
#define NHWC_L1 10240000u   // 200*200*256
#define NHWC_L2 12800000u   // +100*100*256
#define NHWC_L3 13440000u   // +50*50*256
#define NHWC_BS 13600000u   // +25*25*256 (batch stride)

__constant__ int   c_offs[5]  = {0,120000,150000,157500,159375};
__constant__ int   c_gw[5]    = {200,100,50,25,13};
__constant__ float c_stride[5]= {4.f,8.f,16.f,32.f,61.f};
__constant__ float c_size[5]  = {32.f,64.f,128.f,256.f,512.f};
__constant__ int   c_koff[5]  = {0,1000,2000,3000,4000};
__constant__ int   c_k[5]     = {1000,1000,1000,1000,507};
__constant__ float c_ratio[3] = {0.5f,1.f,2.f};

struct PtrArgs { const float* obj[5]; const float* dl[5]; };

__device__ __forceinline__ u32 fkey32f(float x){
  u32 u = __float_as_uint(x);
  return (u & 0x80000000u) ? ~u : (u | 0x80000000u);
}
__device__ __forceinline__ int level_of(int g){
  return (g >= 159375) ? 4 : (g >= 157500) ? 3 : (g >= 150000) ? 2 : (g >= 120000) ? 1 : 0;
}
// broadcast u64 from a wave-uniform lane index (VALU readlane, not ds_bpermute)
__device__ __forceinline__ u64 readlane64(u64 v, int l){
  u32 lo = (u32)v, hi = (u32)(v >> 32);
  u32 a = (u32)__builtin_amdgcn_readlane((int)lo, l);
  u32 b = (u32)__builtin_amdgcn_readlane((int)hi, l);
  return ((u64)b << 32) | (u64)a;
}

// ---------------- 0. zero the global histogram + counters ----------------
__global__ void k_zero(u32* ghist, u32* wcnt, u32* tcnt, int B){
  int n = B*5*65536;
  int idx = blockIdx.x*blockDim.x + threadIdx.x;
  for (int i = idx; i < n; i += gridDim.x*blockDim.x) ghist[i] = 0;
  if (idx < B*5){ wcnt[idx] = 0; tcnt[idx] = 0; }
}

// ---------------- 1. decode all anchors, compute keys + 16-bit histogram ----
__global__ void k_decode(PtrArgs pa, int B, float* boxes_all, u32* key_all, u32* fkey_all,
                         u32* ghist){
#pragma clang fp contract(off)
  int idx = blockIdx.x*blockDim.x + threadIdx.x;
  int total = B*N_ALL;
  if (idx >= total) return;
  int b = idx / N_ALL;
  int g = idx - b*N_ALL;
  int l = level_of(g);
  int n = g - c_offs[l];
  int a = n % 3;
  int pos = n / 3;
  int gw = c_gw[l];
  int wx = pos % gw;
  int hy = pos / gw;
  int plane = gw*gw;
  const float* obj = pa.obj[l];
  const float* dl  = pa.dl[l];
  float logit = obj[(size_t)(b*3 + a)*plane + hy*gw + wx];
  size_t dbase = (size_t)(b*12 + a*4)*plane + (size_t)hy*gw + wx;
  float d0 = dl[dbase];
  float d1 = dl[dbase + (size_t)plane];
  float d2 = dl[dbase + (size_t)2*plane];
  float d3 = dl[dbase + (size_t)3*plane];
  float ratio = c_ratio[a];
  float hr = sqrtf(ratio);
  float wr = 1.0f/hr;
  float wsz = c_size[l]*wr;
  float hsz = c_size[l]*hr;
  float ca0 = rintf(-0.5f*wsz), ca1 = rintf(-0.5f*hsz);
  float ca2 = rintf( 0.5f*wsz), ca3 = rintf( 0.5f*hsz);
  float st = c_stride[l];
  float shx = (float)wx*st, shy = (float)hy*st;
  float ax1 = shx+ca0, ay1 = shy+ca1, ax2 = shx+ca2, ay2 = shy+ca3;
  float w = ax2-ax1, h = ay2-ay1;
  float cx = ax1 + 0.5f*w, cy = ay1 + 0.5f*h;
  float dw = fminf(d2, BBOX_CLIP_F), dh = fminf(d3, BBOX_CLIP_F);
  float pcx = d0*w + cx, pcy = d1*h + cy;
  float pw = expf(dw)*w, ph = expf(dh)*h;
  float x1 = pcx - 0.5f*pw, y1 = pcy - 0.5f*ph;
  float x2 = pcx + 0.5f*pw, y2 = pcy + 0.5f*ph;
  x1 = fminf(fmaxf(x1,0.f),IMGF); y1 = fminf(fmaxf(y1,0.f),IMGF);
  x2 = fminf(fmaxf(x2,0.f),IMGF); y2 = fminf(fmaxf(y2,0.f),IMGF);
  bool valid = ((x2-x1) >= 0.001f) && ((y2-y1) >= 0.001f);
  ((float4*)boxes_all)[idx] = make_float4(x1,y1,x2,y2);
  u32 key = fkey32f(logit);
  key_all[idx] = key;
  atomicAdd(&ghist[(size_t)(b*5 + l)*65536 + (key >> 16)], 1u);
  float sgf = 1.0f/(1.0f + expf(-logit));
  fkey_all[idx] = valid ? fkey32f(sgf) : NEGINF_KEY;
}

// ---------------- 2a. find per-(b,level) threshold bin from histogram --------
// thread t owns bins [t*64,(t+1)*64); suffix-scan of chunk totals in LDS;
// exactly one (t,j) satisfies suffix(bin)>=k && suffix(bin+1)<k.
__global__ __launch_bounds__(1024) void k_sel(const u32* ghist, int2* meta, int B){
  int bl = blockIdx.x;
  int l = bl % 5;
  int k = c_k[l];
  const u32* h = ghist + (size_t)bl*65536;
  __shared__ u32 ssum[1024];
  __shared__ int2 s_meta;
  int tid = threadIdx.x;
  u32 cnt[64];
  u32 tot = 0;
  const uint4* h4 = (const uint4*)(h + tid*64);
  #pragma unroll
  for (int j = 0; j < 16; ++j){
    uint4 v = h4[j];
    cnt[4*j+0]=v.x; cnt[4*j+1]=v.y; cnt[4*j+2]=v.z; cnt[4*j+3]=v.w;
    tot += v.x+v.y+v.z+v.w;
  }
  ssum[tid] = tot;
  __syncthreads();
  for (int s = 1; s < 1024; s <<= 1){
    u32 v = ssum[tid] + ((tid+s < 1024) ? ssum[tid+s] : 0);
    __syncthreads(); ssum[tid] = v; __syncthreads();
  }
  u32 run = (tid+1 < 1024) ? ssum[tid+1] : 0;   // suffix after my chunk
  #pragma unroll
  for (int j = 63; j >= 0; --j){
    u32 cur = run + cnt[j];
    if (cur >= (u32)k && run < (u32)k){ s_meta.x = tid*64 + j; s_meta.y = (int)run; }
    run = cur;
  }
  __syncthreads();
  if (tid == 0) meta[bl] = s_meta;
}

// ---------------- 2b. chunk-parallel emit (set semantics; k_rank re-sorts) ---
__global__ __launch_bounds__(1024) void k_emit(const u32* key_all, const int2* meta,
                                               u32* cand_g, u32* wcnt, u32* tcnt,
                                               u64* tbuf, int B){
  int bid = blockIdx.x;
  int bl = bid / EMIT_S, c = bid - bl*EMIT_S;
  int b = bl / 5, l = bl - b*5;
  int g0 = c_offs[l];
  int N  = ((l==4)?N_ALL:c_offs[l+1]) - g0;
  int CH = (N + EMIT_S - 1)/EMIT_S;
  int st = c*CH, en = st + CH; if (en > N) en = N;
  if (st >= en) return;
  u32 bstar = (u32)meta[bl].x;
  const u32* keys = key_all + (size_t)b*N_ALL + g0;
  u32* out = cand_g + (size_t)b*NC + c_koff[l];
  u64* tb = tbuf + (size_t)bl*4096;
  int tid = threadIdx.x;
  int lane = tid & 63;
  u64 below = lane ? (~0ull >> (64 - lane)) : 0ull;
  for (int i0 = st; i0 < en; i0 += 1024){
    int i = i0 + tid;
    bool inb = (i < en);
    u32 kk = inb ? keys[i] : 0u;
    u32 bin = kk >> 16;
    bool isW = inb && (bin > bstar);
    bool isT = inb && (bin == bstar);
    u64 wb = __ballot(isW);
    if (wb){
      int wn = __popcll(wb);
      int b0 = 0;
      if (lane == 0) b0 = (int)atomicAdd(&wcnt[bl], (u32)wn);
      b0 = __shfl(b0, 0);
      if (isW) out[b0 + __popcll(wb & below)] = (u32)(g0 + i);
    }
    u64 tbm = __ballot(isT);
    if (tbm){
      int tn = __popcll(tbm);
      int b0 = 0;
      if (lane == 0) b0 = (int)atomicAdd(&tcnt[bl], (u32)tn);
      b0 = __shfl(b0, 0);
      if (isT){
        int slot = b0 + __popcll(tbm & below);
        if (slot < 4096) tb[slot] = ((u64)kk << 32) | (u32)(~(u32)(g0 + i));
      }
    }
  }
}

// ---------------- 2c. sort tiny threshold bin, fill out[chi..k) --------------
__global__ __launch_bounds__(1024) void k_fin(const int2* meta, const u32* tcnt,
                                              const u64* tbuf, u32* cand_g, int B){
  int bl = blockIdx.x;
  int b = bl/5, l = bl - b*5;
  int k = c_k[l];
  int chi = meta[bl].y;
  int r = k - chi;
  u32* out = cand_g + (size_t)b*NC + c_koff[l];
  __shared__ u64 buf[4096];
  int tid = threadIdx.x;
  int m = (int)tcnt[bl]; if (m > 4096) m = 4096;
  int P = 1; while (P < m) P <<= 1; if (P < 2) P = 2;
  const u64* tb = tbuf + (size_t)bl*4096;
  for (int i = tid; i < m; i += 1024) buf[i] = tb[i];
  for (int i = m + tid; i < P; i += 1024) buf[i] = 0;
  __syncthreads();
  for (u32 ksz = 2; ksz <= (u32)P; ksz <<= 1){
    for (u32 j = ksz >> 1; j > 0; j >>= 1){
      for (int i = tid; i < P; i += 1024){
        u32 ixj = (u32)i ^ j;
        if (ixj > (u32)i){
          u64 x = buf[i], y = buf[ixj];
          bool up = ((i & ksz) == 0);
          if (up ? (x < y) : (x > y)){ buf[i] = y; buf[ixj] = x; }
        }
      }
      __syncthreads();
    }
  }
  for (int t = tid; t < r && t < m; t += 1024) out[chi + t] = ~(u32)buf[t];
}

// ---------------- 3. per-level rank sort (position order) ----------------
__global__ __launch_bounds__(1024) void k_rank(u32* cand_g, const u32* key_all, int B){
  int blk = blockIdx.x; int b = blk/5, l = blk - b*5;
  int k = c_k[l];
  u32* seg = cand_g + (size_t)b*NC + c_koff[l];
  __shared__ u64 sk[1024];
  int tid = threadIdx.x;
  u64 v = 0;
  if (tid < k){
    u32 g = seg[tid];
    v = ((u64)key_all[(size_t)b*N_ALL + g]<<32) | (u32)(~g);
  }
  sk[tid] = v;
  __syncthreads();
  for (u32 ksz=2;ksz<=1024;ksz<<=1){
    for (u32 j=ksz>>1;j>0;j>>=1){
      int i = tid;
      u32 ixj = (u32)i ^ j;
      if (ixj > (u32)i){
        u64 x = sk[i], y = sk[ixj];
        bool up = ((i & ksz) == 0);
        if (up ? (x < y) : (x > y)){ sk[i]=y; sk[ixj]=x; }
      }
      __syncthreads();
    }
  }
  if (tid < k) seg[tid] = ~(u32)sk[tid];
}

// ---------------- 4. global order by (score desc, position asc) -------------
// Stable partition per level (valid before invalid; bit-identical to sorting
// desc by v=(fkey<<32)|~i given k_rank's order) + 3 merge-path rounds.
__device__ __forceinline__ void merge_elem(const u64* As, const u64* Bs, u64* dst,
                                           int m, int n, int k){
  // descending merge of distinct keys: element at merged position k
  int lo = k - n; if (lo < 0) lo = 0;
  int hi = (k < m) ? k : m;
  while (lo < hi){
    int mid = (lo + hi) >> 1;
    if (As[mid] > Bs[k-1-mid]) lo = mid + 1; else hi = mid;
  }
  int a = lo, bb = k - lo;
  u64 out;
  if (a < m && (bb >= n || As[a] > Bs[bb])) out = As[a]; else out = Bs[bb];
  dst[k] = out;
}

__global__ __launch_bounds__(1024) void k_sortcand(const u32* cand_g, const u32* fkey_all,
                                                   const float* boxes_all,
                                                   float* sorted_box, float* sorted_off,
                                                   u32* fcnt_ws, float* pos0box){
  __shared__ u64 sA[NC];     // 36,056 B
  __shared__ u64 sB[NC];     // 36,056 B
  __shared__ u32 wsum[16];
  __shared__ int s_f;
  int b = blockIdx.x, tid = threadIdx.x;
  int lane = tid & 63, wv = tid >> 6;
  if (tid == 0) s_f = 0;
  size_t cbase = (size_t)b*NC;
  size_t abase = (size_t)b*N_ALL;
  u64 below = lane ? (~0ull >> (64 - lane)) : 0ull;
  // ---- per-level stable partition (valid first), keys into sA ----
  for (int l = 0; l < 5; ++l){
    int kl = c_k[l], ko = c_koff[l];
    bool act = tid < kl;
    u32 fk = 0; bool val = false;
    u32 i_g = (u32)(ko + tid);
    if (act){
      u32 g = cand_g[cbase + i_g];
      fk = fkey_all[abase + g];
      val = fk > NEGINF_KEY;
    }
    u64 bal = __ballot(act && val);
    int pv_w = __popcll(bal & below);
    if (lane == 0) wsum[wv] = (u32)__popcll(bal);
    __syncthreads();
    int pre = 0, Vl = 0;
    #pragma unroll
    for (int w2 = 0; w2 < 16; ++w2){
      int s = (int)wsum[w2];
      if (w2 < wv) pre += s;
      Vl += s;
    }
    if (tid == 0) s_f += Vl;
    if (act){
      int pv = pre + pv_w;
      int pos = val ? pv : (Vl + (tid - pv));
      sA[ko + pos] = ((u64)fk << 32) | (u32)(~i_g);
    }
    __syncthreads();
  }
  // ---- round 1: (L0,L1)->sB[0:2000], (L2,L3)->sB[2000:4000], copy L4 ----
  for (int k = tid; k < NC; k += 1024){
    if (k < 2000)       merge_elem(sA,        sA + 1000, sB,        1000, 1000, k);
    else if (k < 4000)  merge_elem(sA + 2000, sA + 3000, sB + 2000, 1000, 1000, k - 2000);
    else                sB[k] = sA[k];
  }
  __syncthreads();
  // ---- round 2: sB[0:2000]+sB[2000:4000] -> sA[0:4000], copy tail ----
  for (int k = tid; k < NC; k += 1024){
    if (k < 4000) merge_elem(sB, sB + 2000, sA, 2000, 2000, k);
    else          sA[k] = sB[k];
  }
  __syncthreads();
  // ---- round 3: sA[0:4000]+sA[4000:4507] -> sB[0:4507] ----
  for (int k = tid; k < NC; k += 1024){
    merge_elem(sA, sA + 4000, sB, 4000, 507, k);
  }
  __syncthreads();
  // ---- output phase (identical semantics to the old kernel) ----
  for (int i = tid; i < NC; i += 1024){
    u32 posc = ~(u32)sB[i];
    u32 g = cand_g[cbase + posc];
    int lvl = level_of((int)g);
    float4 bx = ((const float4*)boxes_all)[abase + g];
    ((float4*)sorted_box)[cbase + i] = bx;
    float off = 801.0f*(float)lvl;
    ((float4*)sorted_off)[cbase + i] = make_float4(bx.x+off, bx.y+off, bx.z+off, bx.w+off);
  }
  if (tid == 0){
    fcnt_ws[b] = (u32)s_f;
    u32 g0b = cand_g[cbase + 0];          // candidate position 0 (ref padding box)
    float4 bx = ((const float4*)boxes_all)[abase + g0b];
    ((float4*)pos0box)[b] = bx;
  }
}

// ---------------- 5. pairwise suppression bitmask ----------------
__global__ void k_iou(const float* sorted_off, u64* M){
#pragma clang fp contract(off)
  int i = blockIdx.x, b = blockIdx.y, lane = threadIdx.x;
  const float4* boxes = ((const float4*)sorted_off) + (size_t)b*NC;
  float4 bi = boxes[i];
  float a1 = (bi.z-bi.x)*(bi.w-bi.y);
  u64* row = M + ((size_t)b*NC + i)*MROW;
  for (int w=0; w<71; w++){
    int j = w*64 + lane;
    bool sup = false;
    if (j < NC){
      float4 bj = boxes[j];
      float a2 = (bj.z-bj.x)*(bj.w-bj.y);
      float ltx = fmaxf(bi.x,bj.x), lty = fmaxf(bi.y,bj.y);
      float rbx = fminf(bi.z,bj.z), rby = fminf(bi.w,bj.w);
      float wx = fmaxf(rbx-ltx,0.f), wy = fmaxf(rby-lty,0.f);
      float inter = wx*wy;
      float iou = inter/(a1+a2-inter);
      sup = iou > 0.7f;
    }
    u64 word = __ballot(sup);
    if (lane==0) row[w] = word;
  }
}

// ---------------- 6. ballot-Jacobi NMS + reg-depth-2 staging + fused transpose
#define GETQ2(q) { if (t2){ int jj=__builtin_ctzll(t2); t2&=t2-1; q = &buf[cb][jj*72]; } else q = zbuf; }
__global__ __launch_bounds__(256) void k_nms_tr(const float* sorted_box, const u64* M,
                      const u32* fcnt_ws, const float* pos0box, float* props, int B,
                      const float* f0, const float* f1, const float* f2, const float* f3,
                      float* nhwc, int doTr){
  __shared__ u64 buf[2][64*72];     // 73,728 B double buffer
  __shared__ u64 zbuf[72];
  __shared__ int ki[1000];
  __shared__ int s_kc, s_done;
  int bid = blockIdx.x;
  int tid = threadIdx.x;
  if (bid >= B){
    // ---------------- transpose part (aliases buf as 64x65 f32 tile) ------
    float (*t)[65] = reinterpret_cast<float(*)[65]>(&buf[0][0]);
    int id = bid - B;
    int b = id / 3328;
    int rem = id - b*3328;
    int P, W; const float* f; u32 loff;
    if (rem < 2500){ W=200; f=f0; loff=0u; }
    else if (rem < 3128){ W=100; f=f1; loff=NHWC_L1; rem -= 2500; }
    else if (rem < 3288){ W=50;  f=f2; loff=NHWC_L2; rem -= 3128; }
    else { W=25; f=f3; loff=NHWC_L3; rem -= 3288; }
    P = W*W;
    int ctile = rem & 3, ptile = rem >> 2;
    int c0 = ctile*64, p0 = ptile*64;
    const float* src = f + (size_t)b*256*P;
    float* dst = nhwc + (size_t)b*NHWC_BS + loff;
    int q   = tid & 15;        // position quad (phase 1) / channel quad (phase 2)
    int cl0 = tid >> 4;        // 0..15
    bool vec4ok = ((P & 3) == 0);
    int p = p0 + 4*q;
    float4 v[4];
    #pragma unroll
    for (int k = 0; k < 4; ++k){
      int cl = cl0 + 16*k;
      const float* s = src + (size_t)(c0+cl)*P + p;
      if (vec4ok && (p + 3 < P)){
        v[k] = *(const float4*)s;
      } else {
        v[k].x = (p   < P) ? s[0] : 0.f;
        v[k].y = (p+1 < P) ? s[1] : 0.f;
        v[k].z = (p+2 < P) ? s[2] : 0.f;
        v[k].w = (p+3 < P) ? s[3] : 0.f;
      }
    }
    #pragma unroll
    for (int k = 0; k < 4; ++k){
      int cl = cl0 + 16*k;
      t[cl][4*q+0] = v[k].x; t[cl][4*q+1] = v[k].y;
      t[cl][4*q+2] = v[k].z; t[cl][4*q+3] = v[k].w;
    }
    __syncthreads();
    #pragma unroll
    for (int k = 0; k < 4; ++k){
      int pl = cl0 + 16*k;
      int pp = p0 + pl;
      if (pp < P){
        float4 o = make_float4(t[4*q+0][pl], t[4*q+1][pl],
                               t[4*q+2][pl], t[4*q+3][pl]);
        *(float4*)(dst + (size_t)pp*256 + c0 + 4*q) = o;
      }
    }
    return;
  }
  // ---------------- NMS part ----------------
  int b = bid;
  int F = (int)fcnt_ws[b];
  const u64* Mb = M + (size_t)b*NC*MROW;
  int nch = (F + 63) >> 6;
  int lane = tid & 63, wv = tid >> 6;
  if (tid == 0){ s_kc = 0; s_done = (nch == 0) ? 1 : 0; }
  if (tid < 72) zbuf[tid] = 0ull;
  // stage chunk 0 (all 256 threads, direct)
  if (nch > 0){
    for (int e = tid; e < 64*72; e += 256){
      int rr = e / 72, wo = e - rr*72;
      int r2 = rr; if (r2 > NC-1) r2 = NC-1;
      buf[0][e] = Mb[(size_t)r2*MROW + wo];
    }
  }
  // waves 1-3: load chunk 1 into registers (depth-2 pipeline primer)
  u64 rg[24];
  if (wv > 0 && nch > 1){
    #pragma unroll
    for (int k = 0; k < 24; ++k){
      int e = (tid - 64) + k*192;
      int rr = e/72, wo = e - rr*72;
      int r2 = 64 + rr; if (r2 > NC-1) r2 = NC-1;
      rg[k] = Mb[(size_t)r2*MROW + wo];
    }
  }
  __syncthreads();
  u64 sup0 = 0, sup1 = 0;
  int kc = 0;
  for (int c = 0; c < nch; ++c){
    int cb = c & 1;
    if (wv > 0){
      // write chunk c+1 (in regs) to the other buffer; load chunk c+2
      if (c + 1 < nch){
        #pragma unroll
        for (int k = 0; k < 24; ++k){
          int e = (tid - 64) + k*192;
          buf[cb^1][e] = rg[k];
        }
      }
      if (c + 2 < nch){
        int base2 = (c + 2) << 6;
        #pragma unroll
        for (int k = 0; k < 24; ++k){
          int e = (tid - 64) + k*192;
          int rr = e/72, wo = e - rr*72;
          int r2 = base2 + rr; if (r2 > NC-1) r2 = NC-1;
          rg[k] = Mb[(size_t)r2*MROW + wo];
        }
      }
    } else if (kc < 1000){
      int base = c << 6;
      int cnt = F - base; if (cnt > 64) cnt = 64;
      u64 supw = (c < 64) ? readlane64(sup0, c) : readlane64(sup1, c - 64);
      u64 alive = ~supw;
      if (cnt < 64) alive &= ((1ull << cnt) - 1ull);
      u64 wrow = buf[cb][lane*72 + c];   // my row's word for this chunk == my column (symmetric IoU)
      u64 below = lane ? (~0ull >> (64 - lane)) : 0ull;
      u64 colb = wrow & below;           // earlier in-chunk boxes that suppress me
      bool myal = ((alive >> lane) & 1ull) != 0ull;
      u64 kept = __ballot(myal);
      // Jacobi iteration to the unique fixed point == greedy NMS within chunk
      #pragma unroll 1
      for (int it = 0; it < 64; ++it){
        bool kj = myal && ((kept & colb) == 0ull);
        u64 nk = __ballot(kj);
        if (nk == kept) break;
        kept = nk;
      }
      int cnt_k = __popcll(kept);
      int rank  = __popcll(kept & below);
      int budget = 1000 - kc;
      bool sel = ((kept >> lane) & 1ull) && (rank < budget);
      if (sel) ki[kc + rank] = base + lane;
      if (cnt_k >= budget){
        if (lane == 0){ s_done = 1; s_kc = 1000; }
      } else {
        kc += cnt_k;
        // batched OR of kept rows from LDS (16 at a time, zero-row padded)
        u64 t2 = kept;
        while (t2){
          const u64 *q0,*q1,*q2,*q3,*q4,*q5,*q6,*q7;
          const u64 *q8,*q9,*q10,*q11,*q12,*q13,*q14,*q15;
          GETQ2(q0) GETQ2(q1) GETQ2(q2) GETQ2(q3)
          GETQ2(q4) GETQ2(q5) GETQ2(q6) GETQ2(q7)
          GETQ2(q8) GETQ2(q9) GETQ2(q10) GETQ2(q11)
          GETQ2(q12) GETQ2(q13) GETQ2(q14) GETQ2(q15)
          u64 a0=q0[lane],a1=q1[lane],a2=q2[lane],a3=q3[lane];
          u64 a4=q4[lane],a5=q5[lane],a6=q6[lane],a7=q7[lane];
          u64 a8=q8[lane],a9=q9[lane],a10=q10[lane],a11=q11[lane];
          u64 a12=q12[lane],a13=q13[lane],a14=q14[lane],a15=q15[lane];
          sup0 |= (((a0|a1)|(a2|a3))|((a4|a5)|(a6|a7)))
                | (((a8|a9)|(a10|a11))|((a12|a13)|(a14|a15)));
          if (lane < 7){
            u64 b0=q0[64+lane],b1=q1[64+lane],b2=q2[64+lane],b3=q3[64+lane];
            u64 b4=q4[64+lane],b5=q5[64+lane],b6=q6[64+lane],b7=q7[64+lane];
            u64 b8=q8[64+lane],b9=q9[64+lane],b10=q10[64+lane],b11=q11[64+lane];
            u64 b12=q12[64+lane],b13=q13[64+lane],b14=q14[64+lane],b15=q15[64+lane];
            sup1 |= (((b0|b1)|(b2|b3))|((b4|b5)|(b6|b7)))
                  | (((b8|b9)|(b10|b11))|((b12|b13)|(b14|b15)));
          }
        }
        if (lane == 0) s_kc = kc;
      }
    }
    __syncthreads();
    if (s_done) break;      // uniform LDS value across the block
  }
  __syncthreads();
  int kcf = s_kc;
  const float* sb = sorted_box + (size_t)b*NC*4;
  float* pb = props + (size_t)b*4000;
  float4 p0v = ((const float4*)pos0box)[b];
  float pv[4] = {p0v.x, p0v.y, p0v.z, p0v.w};
  for (int idx = tid; idx < 4000; idx += 256){
    int k4 = idx >> 2, comp = idx & 3;
    float v = (k4 < kcf) ? sb[(size_t)ki[k4]*4 + comp] : pv[comp];
    pb[idx] = v;
  }
}

// ---------------- 7a. ROI Align, NHWC path -------------------------------
// Channel-split two-pass (128 ch each): lane quad q=tid&31, pixel slot
// s=tid>>5. obuf[49][132] = 25.9KB -> 4 blocks/CU; epilogue per pass is a
// contiguous coalesced 25KB region. Bit-identical output.
__global__ __launch_bounds__(256, 4) void k_roi_nhwc(const float* nhwc, const float* props,
                                                     float* out){
#pragma clang fp contract(off)
  int r = blockIdx.x;
  int b = r / 1000;
  int tid = threadIdx.x;
  int q = tid & 31;          // channel quad within 128-ch half
  int s = tid >> 5;          // pixel slot 0..7
  __shared__ int   s_o0[196], s_o1[196], s_o2[196], s_o3[196];
  __shared__ float s_a0[196], s_a1[196], s_a2[196], s_a3[196], s_m[196];
  __shared__ float obuf[49*132];     // 25,872 B ; row = 33 float4 (16B-aligned stores)
  float bx0 = props[(size_t)r*4+0], by0 = props[(size_t)r*4+1];
  float bx1 = props[(size_t)r*4+2], by1 = props[(size_t)r*4+3];
  float area = (bx1-bx0)*(by1-by0);
  float v = 4.0f + log2f(sqrtf(area)/224.0f + 1e-6f);
  float fl = floorf(v);
  fl = fminf(fmaxf(fl, 2.0f), 5.0f);
  int li = (int)fl - 2;
  int H = (li==0)?200:(li==1)?100:(li==2)?50:25;
  u32 loff = (li==0)?0u:(li==1)?NHWC_L1:(li==2)?NHWC_L2:NHWC_L3;
  float scale = (li==0)?0.25f:(li==1)?0.125f:(li==2)?0.0625f:0.03125f;
  float x1 = bx0*scale, y1 = by0*scale, x2 = bx1*scale, y2 = by1*scale;
  float rw = fmaxf(x2-x1, 1.0f), rh = fmaxf(y2-y1, 1.0f);
  if (tid < 196){
    int syi = tid / 14, sxi = tid - syi*14;
    float ty = ((float)syi + 0.5f)/14.0f;
    float yv = y1 + rh*ty;
    float fy = (yv >= -1.0f && yv <= (float)H) ? 1.0f : 0.0f;
    float yc = fminf(fmaxf(yv,0.0f),(float)(H-1));
    int iy0 = (int)floorf(yc);
    int iy1 = min(iy0+1,H-1);
    float ly = yc-(float)iy0;
    float tx = ((float)sxi + 0.5f)/14.0f;
    float xv = x1 + rw*tx;
    float fx = (xv >= -1.0f && xv <= (float)H) ? 1.0f : 0.0f;
    float xc = fminf(fmaxf(xv,0.0f),(float)(H-1));
    int ix0 = (int)floorf(xc);
    int ix1 = min(ix0+1,H-1);
    float lx = xc-(float)ix0;
    s_o0[tid] = (iy0*H + ix0)*64;    // offsets in float4 units
    s_o1[tid] = (iy0*H + ix1)*64;
    s_o2[tid] = (iy1*H + ix0)*64;
    s_o3[tid] = (iy1*H + ix1)*64;
    s_a0[tid] = (1.f-ly)*(1.f-lx);
    s_a1[tid] = (1.f-ly)*lx;
    s_a2[tid] = ly*(1.f-lx);
    s_a3[tid] = ly*lx;
    s_m[tid]  = fy*fx;
  }
  __syncthreads();
  const float4* src4 = (const float4*)(nhwc + (size_t)b*NHWC_BS + loff);
  float4* obuf4 = (float4*)obuf;
  float* orow = out + (size_t)r*12544;
  #pragma unroll 1
  for (int h = 0; h < 2; ++h){
    int qh = h*32 + q;
    for (int p = s; p < 49; p += 8){
      int py = p/7, px = p - py*7;
      float accx = 0.f, accy = 0.f, accz = 0.f, accw = 0.f;
      #pragma unroll
      for (int iy = 0; iy < 2; ++iy){
        #pragma unroll
        for (int ix = 0; ix < 2; ++ix){
          int sp = (py*2+iy)*14 + (px*2+ix);
          int o00 = s_o0[sp], o01 = s_o1[sp], o10 = s_o2[sp], o11 = s_o3[sp];
          float a00 = s_a0[sp], a01 = s_a1[sp], a10 = s_a2[sp], a11 = s_a3[sp];
          float m = s_m[sp];
          float4 v00 = src4[o00 + qh];
          float4 v01 = src4[o01 + qh];
          float4 v10 = src4[o10 + qh];
          float4 v11 = src4[o11 + qh];
          accx += (a00*v00.x + a01*v01.x + a10*v10.x + a11*v11.x)*m;
          accy += (a00*v00.y + a01*v01.y + a10*v10.y + a11*v11.y)*m;
          accz += (a00*v00.z + a01*v01.z + a10*v10.z + a11*v11.z)*m;
          accw += (a00*v00.w + a01*v01.w + a10*v10.w + a11*v11.w)*m;
        }
      }
      obuf4[p*33 + q] = make_float4(accx*0.25f, accy*0.25f, accz*0.25f, accw*0.25f);
    }
    __syncthreads();
    // contiguous coalesced epilogue: channels [h*128,(h+1)*128) x 49 pixels
    for (int o = tid; o < 6272; o += 256){
      int c = o/49, p = o - c*49;
      orow[h*6272 + o] = obuf[p*132 + c];
    }
    __syncthreads();       // obuf reused next pass
  }
}

// ---------------- 7b. ROI Align, direct-NCHW fallback ----------------------
__global__ __launch_bounds__(256) void k_roi(const float* f0, const float* f1,
                                             const float* f2, const float* f3,
                                             const float* props, float* out){
#pragma clang fp contract(off)
  int r = blockIdx.x;
  int b = r / 1000;
  int tid = threadIdx.x;
  __shared__ float s_ly[14], s_lx[14], s_ym[14], s_xm[14];
  __shared__ int   s_y0[14], s_y1[14], s_x0[14], s_x1[14];
  float bx0 = props[(size_t)r*4+0], by0 = props[(size_t)r*4+1];
  float bx1 = props[(size_t)r*4+2], by1 = props[(size_t)r*4+3];
  float area = (bx1-bx0)*(by1-by0);
  float v = 4.0f + log2f(sqrtf(area)/224.0f + 1e-6f);
  float fl = floorf(v);
  fl = fminf(fmaxf(fl, 2.0f), 5.0f);
  int li = (int)fl - 2;
  const float* fptr = (li==0)?f0:(li==1)?f1:(li==2)?f2:f3;
  int H = (li==0)?200:(li==1)?100:(li==2)?50:25;
  float scale = (li==0)?0.25f:(li==1)?0.125f:(li==2)?0.0625f:0.03125f;
  float x1 = bx0*scale, y1 = by0*scale, x2 = bx1*scale, y2 = by1*scale;
  float rw = fmaxf(x2-x1, 1.0f), rh = fmaxf(y2-y1, 1.0f);
  if (tid < 14){
    float t = ((float)tid + 0.5f)/14.0f;
    float yv = y1 + rh*t;
    s_ym[tid] = (yv >= -1.0f && yv <= (float)H) ? 1.0f : 0.0f;
    float yc = fminf(fmaxf(yv,0.0f),(float)(H-1));
    int iy0 = (int)floorf(yc);
    s_y0[tid]=iy0; s_y1[tid]=min(iy0+1,H-1); s_ly[tid]=yc-(float)iy0;
    float xv = x1 + rw*t;
    s_xm[tid] = (xv >= -1.0f && xv <= (float)H) ? 1.0f : 0.0f;
    float xc = fminf(fmaxf(xv,0.0f),(float)(H-1));
    int ix0 = (int)floorf(xc);
    s_x0[tid]=ix0; s_x1[tid]=min(ix0+1,H-1); s_lx[tid]=xc-(float)ix0;
  }
  __syncthreads();
  size_t plane = (size_t)H*H;
  const float* fb = fptr + (size_t)b*256*plane;
  float* orow = out + (size_t)r*12544;
  for (int o=tid; o<12544; o+=256){
    int c = o/49;
    int p = o - c*49;
    int py = p/7, px = p - py*7;
    const float* fc = fb + (size_t)c*plane;
    float sum = 0.f;
    for (int iy=0; iy<2; iy++){
      int syi = py*2+iy;
      int yy0 = s_y0[syi], yy1 = s_y1[syi];
      float ly = s_ly[syi], fy = s_ym[syi];
      for (int ix=0; ix<2; ix++){
        int sxi = px*2+ix;
        int xx0 = s_x0[sxi], xx1 = s_x1[sxi];
        float lx = s_lx[sxi], fx = s_xm[sxi];
        float v00 = fc[yy0*H+xx0], v01 = fc[yy0*H+xx1];
        float v10 = fc[yy1*H+xx0], v11 = fc[yy1*H+xx1];
        float val = ((1.f-ly)*(1.f-lx)*v00 + (1.f-ly)*lx*v01
                   + ly*(1.f-lx)*v10 + ly*lx*v11) * (fy*fx);
        sum += val;
      }
    }
    orow[o] = sum*0.25f;
  }
}

extern "C" void kernel_launch(void* const* d_in, const int* in_sizes, int n_in,
                              void* d_out, int out_size, void* d_ws, size_t ws_size,
                              hipStream_t stream) {
  int B = in_sizes[0] / (3*800*800);
  PtrArgs pa;
  bool interleaved = (n_in >= 7) && (in_sizes[6] == 4*in_sizes[5]);
  for (int i=0;i<5;i++){
    if (interleaved){
      pa.obj[i] = (const float*)d_in[5+2*i];
      pa.dl[i]  = (const float*)d_in[6+2*i];
    } else {
      pa.obj[i] = (const float*)d_in[5+i];
      pa.dl[i]  = (const float*)d_in[10+i];
    }
  }

  // ---- small scratch in the TAIL of d_out (overwritten last by ROI) ----
  auto align256 = [](size_t x){ return (x + 255) & ~(size_t)255; };
  size_t sz_M      = align256(((size_t)B*NC + 1)*MROW*8);
  size_t sz_boxes  = align256((size_t)B*N_ALL*16);
  size_t sz_key    = align256((size_t)B*N_ALL*4);
  size_t sz_fkey   = align256((size_t)B*N_ALL*4);
  size_t sz_cand   = align256((size_t)B*NC*4);
  size_t sz_sbox   = align256((size_t)B*NC*16);
  size_t sz_soff   = align256((size_t)B*NC*16);
  size_t sz_fcnt   = align256((size_t)B*4);
  size_t sz_p0     = align256((size_t)B*16);
  size_t sz_ghist  = align256((size_t)B*5*65536*4);
  size_t sz_meta   = align256((size_t)B*5*8);
  size_t sz_wcnt   = align256((size_t)B*5*4);
  size_t sz_tcnt   = align256((size_t)B*5*4);
  size_t sz_tbuf   = align256((size_t)B*5*4096*8);
  size_t need = sz_M+sz_boxes+sz_key+sz_fkey+sz_cand+sz_sbox+sz_soff+sz_fcnt+sz_p0
              + sz_ghist+sz_meta+sz_wcnt+sz_tcnt+sz_tbuf;
  size_t outBytes = (size_t)out_size * 4;
  size_t start = (outBytes - need) & ~(size_t)255;
  char* w = (char*)d_out + start;
  auto alloc = [&](size_t bytes)->char*{ char* p = w; w += bytes; return p; };

  u64*  M          = (u64*) alloc(sz_M);
  float* boxes_all = (float*)alloc(sz_boxes);
  u32*  key_all    = (u32*) alloc(sz_key);
  u32*  fkey_all   = (u32*) alloc(sz_fkey);
  u32*  cand_g     = (u32*) alloc(sz_cand);
  float* sorted_box= (float*)alloc(sz_sbox);
  float* sorted_off= (float*)alloc(sz_soff);
  u32*  fcnt       = (u32*) alloc(sz_fcnt);
  float* pos0box   = (float*)alloc(sz_p0);
  u32*  ghist      = (u32*) alloc(sz_ghist);
  int2* meta       = (int2*)alloc(sz_meta);
  u32*  wcnt       = (u32*) alloc(sz_wcnt);
  u32*  tcnt       = (u32*) alloc(sz_tcnt);
  u64*  tbuf       = (u64*) alloc(sz_tbuf);

  float* props     = (float*)d_out;
  float* feats_out = (float*)d_out + (size_t)B*1000*4;

  int total = B*N_ALL;
  k_zero<<<2560, 256, 0, stream>>>(ghist, wcnt, tcnt, B);
  k_decode<<<(total+255)/256, 256, 0, stream>>>(pa, B, boxes_all, key_all, fkey_all, ghist);
  k_sel<<<B*5, 1024, 0, stream>>>(ghist, meta, B);
  k_emit<<<B*5*EMIT_S, 1024, 0, stream>>>(key_all, meta, cand_g, wcnt, tcnt, tbuf, B);
  k_fin<<<B*5, 1024, 0, stream>>>(meta, tcnt, tbuf, cand_g, B);
  k_rank<<<B*5, 1024, 0, stream>>>(cand_g, key_all, B);
  k_sortcand<<<B, 1024, 0, stream>>>(cand_g, fkey_all, boxes_all, sorted_box, sorted_off, fcnt, pos0box);
  k_iou<<<dim3(NC, B), 64, 0, stream>>>(sorted_off, M);

  size_t nhwcBytes = (size_t)B * NHWC_BS * 4;
  int doTr = (ws_size >= nhwcBytes) ? 1 : 0;
  float* nhwc = (float*)d_ws;
  int grid = B + (doTr ? B*3328 : 0);
  k_nms_tr<<<grid, 256, 0, stream>>>(sorted_box, M, fcnt, pos0box, props, B,
                                     (const float*)d_in[1], (const float*)d_in[2],
                                     (const float*)d_in[3], (const float*)d_in[4],
                                     nhwc, doTr);
  if (doTr){
    k_roi_nhwc<<<B*1000, 256, 0, stream>>>(nhwc, props, feats_out);
  } else {
    k_roi<<<B*1000, 256, 0, stream>>>((const float*)d_in[1], (const float*)d_in[2],
                                      (const float*)d_in[3], (const float*)d_in[4],
                                      props, feats_out);
  }
}

// Round 7
// 301.750 us; speedup vs baseline: 1.2140x; 1.2140x over previous
//
#include <hip/hip_runtime.h>
#include <math.h>

typedef unsigned int u32;
typedef unsigned long long u64;

#define N_ALL 159882
#define NC 4507
#define MROW 72
#define NEGINF_KEY 0x007FFFFFu
#define IMGF 800.0f
#define BBOX_CLIP_F 4.135166556742356f
#define EMIT_S 16
#define HBINS 16384
#define HCH 16

// NHWC scratch geometry (floats, per batch)
#define NHWC_L1 10240000u   // 200*200*256
#define NHWC_L2 12800000u   // +100*100*256
#define NHWC_L3 13440000u   // +50*50*256
#define NHWC_BS 13600000u   // +25*25*256 (batch stride)

__constant__ int   c_offs[5]  = {0,120000,150000,157500,159375};
__constant__ int   c_gw[5]    = {200,100,50,25,13};
__constant__ float c_stride[5]= {4.f,8.f,16.f,32.f,61.f};
__constant__ float c_size[5]  = {32.f,64.f,128.f,256.f,512.f};
__constant__ int   c_koff[5]  = {0,1000,2000,3000,4000};
__constant__ int   c_k[5]     = {1000,1000,1000,1000,507};
__constant__ float c_ratio[3] = {0.5f,1.f,2.f};

struct PtrArgs { const float* obj[5]; const float* dl[5]; };

__device__ __forceinline__ u32 fkey32f(float x){
  u32 u = __float_as_uint(x);
  return (u & 0x80000000u) ? ~u : (u | 0x80000000u);
}
__device__ __forceinline__ int level_of(int g){
  return (g >= 159375) ? 4 : (g >= 157500) ? 3 : (g >= 150000) ? 2 : (g >= 120000) ? 1 : 0;
}
// broadcast u64 from a wave-uniform lane index (VALU readlane, not ds_bpermute)
__device__ __forceinline__ u64 readlane64(u64 v, int l){
  u32 lo = (u32)v, hi = (u32)(v >> 32);
  u32 a = (u32)__builtin_amdgcn_readlane((int)lo, l);
  u32 b = (u32)__builtin_amdgcn_readlane((int)hi, l);
  return ((u64)b << 32) | (u64)a;
}

// ---------------- 0. zero the global histogram + counters ----------------
__global__ void k_zero(u32* ghist, u32* wcnt, u32* tcnt, int B){
  int n = B*5*HBINS;
  int idx = blockIdx.x*blockDim.x + threadIdx.x;
  for (int i = idx; i < n; i += gridDim.x*blockDim.x) ghist[i] = 0;
  if (idx < B*5){ wcnt[idx] = 0; tcnt[idx] = 0; }
}

// ---------------- 1. decode all anchors, compute keys (round-5 form) --------
__global__ void k_decode(PtrArgs pa, int B, float* boxes_all, u32* key_all, u32* fkey_all){
#pragma clang fp contract(off)
  int idx = blockIdx.x*blockDim.x + threadIdx.x;
  int total = B*N_ALL;
  if (idx >= total) return;
  int b = idx / N_ALL;
  int g = idx - b*N_ALL;
  int l = level_of(g);
  int n = g - c_offs[l];
  int a = n % 3;
  int pos = n / 3;
  int gw = c_gw[l];
  int wx = pos % gw;
  int hy = pos / gw;
  int plane = gw*gw;
  const float* obj = pa.obj[l];
  const float* dl  = pa.dl[l];
  float logit = obj[(size_t)(b*3 + a)*plane + hy*gw + wx];
  size_t dbase = (size_t)(b*12 + a*4)*plane + (size_t)hy*gw + wx;
  float d0 = dl[dbase];
  float d1 = dl[dbase + (size_t)plane];
  float d2 = dl[dbase + (size_t)2*plane];
  float d3 = dl[dbase + (size_t)3*plane];
  float ratio = c_ratio[a];
  float hr = sqrtf(ratio);
  float wr = 1.0f/hr;
  float wsz = c_size[l]*wr;
  float hsz = c_size[l]*hr;
  float ca0 = rintf(-0.5f*wsz), ca1 = rintf(-0.5f*hsz);
  float ca2 = rintf( 0.5f*wsz), ca3 = rintf( 0.5f*hsz);
  float st = c_stride[l];
  float shx = (float)wx*st, shy = (float)hy*st;
  float ax1 = shx+ca0, ay1 = shy+ca1, ax2 = shx+ca2, ay2 = shy+ca3;
  float w = ax2-ax1, h = ay2-ay1;
  float cx = ax1 + 0.5f*w, cy = ay1 + 0.5f*h;
  float dw = fminf(d2, BBOX_CLIP_F), dh = fminf(d3, BBOX_CLIP_F);
  float pcx = d0*w + cx, pcy = d1*h + cy;
  float pw = expf(dw)*w, ph = expf(dh)*h;
  float x1 = pcx - 0.5f*pw, y1 = pcy - 0.5f*ph;
  float x2 = pcx + 0.5f*pw, y2 = pcy + 0.5f*ph;
  x1 = fminf(fmaxf(x1,0.f),IMGF); y1 = fminf(fmaxf(y1,0.f),IMGF);
  x2 = fminf(fmaxf(x2,0.f),IMGF); y2 = fminf(fmaxf(y2,0.f),IMGF);
  bool valid = ((x2-x1) >= 0.001f) && ((y2-y1) >= 0.001f);
  ((float4*)boxes_all)[idx] = make_float4(x1,y1,x2,y2);
  key_all[idx] = fkey32f(logit);
  float sgf = 1.0f/(1.0f + expf(-logit));
  fkey_all[idx] = valid ? fkey32f(sgf) : NEGINF_KEY;
}

// ---------------- 1b. 14-bit histogram, LDS-privatized per chunk ------------
// Round-6 lesson: fused global scattered atomics in k_decode serialized on
// hot bins (+56us). Here each chunk-block builds its own LDS histogram
// (hot-bin collisions cost ~4cy in LDS, not L2 round-trips), then merges
// only non-zero bins to global (<=HCH contenders per bin, no hotspots).
__global__ __launch_bounds__(256) void k_hist(const u32* key_all, u32* ghist, int B){
  __shared__ u32 lh[HBINS];    // 64 KiB
  int bid = blockIdx.x;
  int bl = bid / HCH, c = bid - bl*HCH;
  int b = bl / 5, l = bl - b*5;
  int g0 = c_offs[l];
  int N  = ((l==4)?N_ALL:c_offs[l+1]) - g0;
  int CH = (N + HCH - 1)/HCH;
  int st = c*CH, en = st + CH; if (en > N) en = N;
  int tid = threadIdx.x;
  for (int i = tid; i < HBINS; i += 256) lh[i] = 0;
  __syncthreads();
  if (st < en){
    const u32* keys = key_all + (size_t)b*N_ALL + g0;
    for (int i = st + tid; i < en; i += 256)
      atomicAdd(&lh[keys[i] >> 18], 1u);
  }
  __syncthreads();
  u32* gh = ghist + (size_t)bl*HBINS;
  for (int i = tid; i < HBINS; i += 256){
    u32 v = lh[i];
    if (v) atomicAdd(&gh[i], v);
  }
}

// ---------------- 2a. find per-(b,level) threshold bin from histogram --------
// thread t owns bins [t*16,(t+1)*16); suffix-scan of chunk totals in LDS;
// exactly one (t,j) satisfies suffix(bin)>=k && suffix(bin+1)<k.
__global__ __launch_bounds__(1024) void k_sel(const u32* ghist, int2* meta, int B){
  int bl = blockIdx.x;
  int l = bl % 5;
  int k = c_k[l];
  const u32* h = ghist + (size_t)bl*HBINS;
  __shared__ u32 ssum[1024];
  __shared__ int2 s_meta;
  int tid = threadIdx.x;
  u32 cnt[16];
  u32 tot = 0;
  const uint4* h4 = (const uint4*)(h + tid*16);
  #pragma unroll
  for (int j = 0; j < 4; ++j){
    uint4 v = h4[j];
    cnt[4*j+0]=v.x; cnt[4*j+1]=v.y; cnt[4*j+2]=v.z; cnt[4*j+3]=v.w;
    tot += v.x+v.y+v.z+v.w;
  }
  ssum[tid] = tot;
  __syncthreads();
  for (int s = 1; s < 1024; s <<= 1){
    u32 v = ssum[tid] + ((tid+s < 1024) ? ssum[tid+s] : 0);
    __syncthreads(); ssum[tid] = v; __syncthreads();
  }
  u32 run = (tid+1 < 1024) ? ssum[tid+1] : 0;   // suffix after my chunk
  #pragma unroll
  for (int j = 15; j >= 0; --j){
    u32 cur = run + cnt[j];
    if (cur >= (u32)k && run < (u32)k){ s_meta.x = tid*16 + j; s_meta.y = (int)run; }
    run = cur;
  }
  __syncthreads();
  if (tid == 0) meta[bl] = s_meta;
}

// ---------------- 2b. chunk-parallel emit (set semantics; k_rank re-sorts) ---
__global__ __launch_bounds__(1024) void k_emit(const u32* key_all, const int2* meta,
                                               u32* cand_g, u32* wcnt, u32* tcnt,
                                               u64* tbuf, int B){
  int bid = blockIdx.x;
  int bl = bid / EMIT_S, c = bid - bl*EMIT_S;
  int b = bl / 5, l = bl - b*5;
  int g0 = c_offs[l];
  int N  = ((l==4)?N_ALL:c_offs[l+1]) - g0;
  int CH = (N + EMIT_S - 1)/EMIT_S;
  int st = c*CH, en = st + CH; if (en > N) en = N;
  if (st >= en) return;
  u32 bstar = (u32)meta[bl].x;
  const u32* keys = key_all + (size_t)b*N_ALL + g0;
  u32* out = cand_g + (size_t)b*NC + c_koff[l];
  u64* tb = tbuf + (size_t)bl*4096;
  int tid = threadIdx.x;
  int lane = tid & 63;
  u64 below = lane ? (~0ull >> (64 - lane)) : 0ull;
  for (int i0 = st; i0 < en; i0 += 1024){
    int i = i0 + tid;
    bool inb = (i < en);
    u32 kk = inb ? keys[i] : 0u;
    u32 bin = kk >> 18;
    bool isW = inb && (bin > bstar);
    bool isT = inb && (bin == bstar);
    u64 wb = __ballot(isW);
    if (wb){
      int wn = __popcll(wb);
      int b0 = 0;
      if (lane == 0) b0 = (int)atomicAdd(&wcnt[bl], (u32)wn);
      b0 = __shfl(b0, 0);
      if (isW) out[b0 + __popcll(wb & below)] = (u32)(g0 + i);
    }
    u64 tbm = __ballot(isT);
    if (tbm){
      int tn = __popcll(tbm);
      int b0 = 0;
      if (lane == 0) b0 = (int)atomicAdd(&tcnt[bl], (u32)tn);
      b0 = __shfl(b0, 0);
      if (isT){
        int slot = b0 + __popcll(tbm & below);
        if (slot < 4096) tb[slot] = ((u64)kk << 32) | (u32)(~(u32)(g0 + i));
      }
    }
  }
}

// ---------------- 2c. sort tiny threshold bin, fill out[chi..k) --------------
__global__ __launch_bounds__(1024) void k_fin(const int2* meta, const u32* tcnt,
                                              const u64* tbuf, u32* cand_g, int B){
  int bl = blockIdx.x;
  int b = bl/5, l = bl - b*5;
  int k = c_k[l];
  int chi = meta[bl].y;
  int r = k - chi;
  u32* out = cand_g + (size_t)b*NC + c_koff[l];
  __shared__ u64 buf[4096];
  int tid = threadIdx.x;
  int m = (int)tcnt[bl]; if (m > 4096) m = 4096;
  int P = 1; while (P < m) P <<= 1; if (P < 2) P = 2;
  const u64* tb = tbuf + (size_t)bl*4096;
  for (int i = tid; i < m; i += 1024) buf[i] = tb[i];
  for (int i = m + tid; i < P; i += 1024) buf[i] = 0;
  __syncthreads();
  for (u32 ksz = 2; ksz <= (u32)P; ksz <<= 1){
    for (u32 j = ksz >> 1; j > 0; j >>= 1){
      for (int i = tid; i < P; i += 1024){
        u32 ixj = (u32)i ^ j;
        if (ixj > (u32)i){
          u64 x = buf[i], y = buf[ixj];
          bool up = ((i & ksz) == 0);
          if (up ? (x < y) : (x > y)){ buf[i] = y; buf[ixj] = x; }
        }
      }
      __syncthreads();
    }
  }
  for (int t = tid; t < r && t < m; t += 1024) out[chi + t] = ~(u32)buf[t];
}

// ---------------- 3. per-level rank sort (position order) ----------------
__global__ __launch_bounds__(1024) void k_rank(u32* cand_g, const u32* key_all, int B){
  int blk = blockIdx.x; int b = blk/5, l = blk - b*5;
  int k = c_k[l];
  u32* seg = cand_g + (size_t)b*NC + c_koff[l];
  __shared__ u64 sk[1024];
  int tid = threadIdx.x;
  u64 v = 0;
  if (tid < k){
    u32 g = seg[tid];
    v = ((u64)key_all[(size_t)b*N_ALL + g]<<32) | (u32)(~g);
  }
  sk[tid] = v;
  __syncthreads();
  for (u32 ksz=2;ksz<=1024;ksz<<=1){
    for (u32 j=ksz>>1;j>0;j>>=1){
      int i = tid;
      u32 ixj = (u32)i ^ j;
      if (ixj > (u32)i){
        u64 x = sk[i], y = sk[ixj];
        bool up = ((i & ksz) == 0);
        if (up ? (x < y) : (x > y)){ sk[i]=y; sk[ixj]=x; }
      }
      __syncthreads();
    }
  }
  if (tid < k) seg[tid] = ~(u32)sk[tid];
}

// ---------------- 4. global order by (score desc, position asc) -------------
// Stable partition per level (valid before invalid; bit-identical to sorting
// desc by v=(fkey<<32)|~i given k_rank's order) + 3 merge-path rounds.
__device__ __forceinline__ void merge_elem(const u64* As, const u64* Bs, u64* dst,
                                           int m, int n, int k){
  // descending merge of distinct keys: element at merged position k
  int lo = k - n; if (lo < 0) lo = 0;
  int hi = (k < m) ? k : m;
  while (lo < hi){
    int mid = (lo + hi) >> 1;
    if (As[mid] > Bs[k-1-mid]) lo = mid + 1; else hi = mid;
  }
  int a = lo, bb = k - lo;
  u64 out;
  if (a < m && (bb >= n || As[a] > Bs[bb])) out = As[a]; else out = Bs[bb];
  dst[k] = out;
}

__global__ __launch_bounds__(1024) void k_sortcand(const u32* cand_g, const u32* fkey_all,
                                                   const float* boxes_all,
                                                   float* sorted_box, float* sorted_off,
                                                   u32* fcnt_ws, float* pos0box){
  __shared__ u64 sA[NC];     // 36,056 B
  __shared__ u64 sB[NC];     // 36,056 B
  __shared__ u32 wsum[16];
  __shared__ int s_f;
  int b = blockIdx.x, tid = threadIdx.x;
  int lane = tid & 63, wv = tid >> 6;
  if (tid == 0) s_f = 0;
  size_t cbase = (size_t)b*NC;
  size_t abase = (size_t)b*N_ALL;
  u64 below = lane ? (~0ull >> (64 - lane)) : 0ull;
  // ---- per-level stable partition (valid first), keys into sA ----
  for (int l = 0; l < 5; ++l){
    int kl = c_k[l], ko = c_koff[l];
    bool act = tid < kl;
    u32 fk = 0; bool val = false;
    u32 i_g = (u32)(ko + tid);
    if (act){
      u32 g = cand_g[cbase + i_g];
      fk = fkey_all[abase + g];
      val = fk > NEGINF_KEY;
    }
    u64 bal = __ballot(act && val);
    int pv_w = __popcll(bal & below);
    if (lane == 0) wsum[wv] = (u32)__popcll(bal);
    __syncthreads();
    int pre = 0, Vl = 0;
    #pragma unroll
    for (int w2 = 0; w2 < 16; ++w2){
      int s = (int)wsum[w2];
      if (w2 < wv) pre += s;
      Vl += s;
    }
    if (tid == 0) s_f += Vl;
    if (act){
      int pv = pre + pv_w;
      int pos = val ? pv : (Vl + (tid - pv));
      sA[ko + pos] = ((u64)fk << 32) | (u32)(~i_g);
    }
    __syncthreads();
  }
  // ---- round 1: (L0,L1)->sB[0:2000], (L2,L3)->sB[2000:4000], copy L4 ----
  for (int k = tid; k < NC; k += 1024){
    if (k < 2000)       merge_elem(sA,        sA + 1000, sB,        1000, 1000, k);
    else if (k < 4000)  merge_elem(sA + 2000, sA + 3000, sB + 2000, 1000, 1000, k - 2000);
    else                sB[k] = sA[k];
  }
  __syncthreads();
  // ---- round 2: sB[0:2000]+sB[2000:4000] -> sA[0:4000], copy tail ----
  for (int k = tid; k < NC; k += 1024){
    if (k < 4000) merge_elem(sB, sB + 2000, sA, 2000, 2000, k);
    else          sA[k] = sB[k];
  }
  __syncthreads();
  // ---- round 3: sA[0:4000]+sA[4000:4507] -> sB[0:4507] ----
  for (int k = tid; k < NC; k += 1024){
    merge_elem(sA, sA + 4000, sB, 4000, 507, k);
  }
  __syncthreads();
  // ---- output phase (identical semantics to the old kernel) ----
  for (int i = tid; i < NC; i += 1024){
    u32 posc = ~(u32)sB[i];
    u32 g = cand_g[cbase + posc];
    int lvl = level_of((int)g);
    float4 bx = ((const float4*)boxes_all)[abase + g];
    ((float4*)sorted_box)[cbase + i] = bx;
    float off = 801.0f*(float)lvl;
    ((float4*)sorted_off)[cbase + i] = make_float4(bx.x+off, bx.y+off, bx.z+off, bx.w+off);
  }
  if (tid == 0){
    fcnt_ws[b] = (u32)s_f;
    u32 g0b = cand_g[cbase + 0];          // candidate position 0 (ref padding box)
    float4 bx = ((const float4*)boxes_all)[abase + g0b];
    ((float4*)pos0box)[b] = bx;
  }
}

// ---------------- 5. pairwise suppression bitmask ----------------
__global__ void k_iou(const float* sorted_off, u64* M){
#pragma clang fp contract(off)
  int i = blockIdx.x, b = blockIdx.y, lane = threadIdx.x;
  const float4* boxes = ((const float4*)sorted_off) + (size_t)b*NC;
  float4 bi = boxes[i];
  float a1 = (bi.z-bi.x)*(bi.w-bi.y);
  u64* row = M + ((size_t)b*NC + i)*MROW;
  for (int w=0; w<71; w++){
    int j = w*64 + lane;
    bool sup = false;
    if (j < NC){
      float4 bj = boxes[j];
      float a2 = (bj.z-bj.x)*(bj.w-bj.y);
      float ltx = fmaxf(bi.x,bj.x), lty = fmaxf(bi.y,bj.y);
      float rbx = fminf(bi.z,bj.z), rby = fminf(bi.w,bj.w);
      float wx = fmaxf(rbx-ltx,0.f), wy = fmaxf(rby-lty,0.f);
      float inter = wx*wy;
      float iou = inter/(a1+a2-inter);
      sup = iou > 0.7f;
    }
    u64 word = __ballot(sup);
    if (lane==0) row[w] = word;
  }
}

// ---------------- 6. ballot-Jacobi NMS + reg-depth-2 staging + fused transpose
#define GETQ2(q) { if (t2){ int jj=__builtin_ctzll(t2); t2&=t2-1; q = &buf[cb][jj*72]; } else q = zbuf; }
__global__ __launch_bounds__(256) void k_nms_tr(const float* sorted_box, const u64* M,
                      const u32* fcnt_ws, const float* pos0box, float* props, int B,
                      const float* f0, const float* f1, const float* f2, const float* f3,
                      float* nhwc, int doTr){
  __shared__ u64 buf[2][64*72];     // 73,728 B double buffer
  __shared__ u64 zbuf[72];
  __shared__ int ki[1000];
  __shared__ int s_kc, s_done;
  int bid = blockIdx.x;
  int tid = threadIdx.x;
  if (bid >= B){
    // ---------------- transpose part (aliases buf as 64x65 f32 tile) ------
    float (*t)[65] = reinterpret_cast<float(*)[65]>(&buf[0][0]);
    int id = bid - B;
    int b = id / 3328;
    int rem = id - b*3328;
    int P, W; const float* f; u32 loff;
    if (rem < 2500){ W=200; f=f0; loff=0u; }
    else if (rem < 3128){ W=100; f=f1; loff=NHWC_L1; rem -= 2500; }
    else if (rem < 3288){ W=50;  f=f2; loff=NHWC_L2; rem -= 3128; }
    else { W=25; f=f3; loff=NHWC_L3; rem -= 3288; }
    P = W*W;
    int ctile = rem & 3, ptile = rem >> 2;
    int c0 = ctile*64, p0 = ptile*64;
    const float* src = f + (size_t)b*256*P;
    float* dst = nhwc + (size_t)b*NHWC_BS + loff;
    int q   = tid & 15;        // position quad (phase 1) / channel quad (phase 2)
    int cl0 = tid >> 4;        // 0..15
    bool vec4ok = ((P & 3) == 0);
    int p = p0 + 4*q;
    float4 v[4];
    #pragma unroll
    for (int k = 0; k < 4; ++k){
      int cl = cl0 + 16*k;
      const float* s = src + (size_t)(c0+cl)*P + p;
      if (vec4ok && (p + 3 < P)){
        v[k] = *(const float4*)s;
      } else {
        v[k].x = (p   < P) ? s[0] : 0.f;
        v[k].y = (p+1 < P) ? s[1] : 0.f;
        v[k].z = (p+2 < P) ? s[2] : 0.f;
        v[k].w = (p+3 < P) ? s[3] : 0.f;
      }
    }
    #pragma unroll
    for (int k = 0; k < 4; ++k){
      int cl = cl0 + 16*k;
      t[cl][4*q+0] = v[k].x; t[cl][4*q+1] = v[k].y;
      t[cl][4*q+2] = v[k].z; t[cl][4*q+3] = v[k].w;
    }
    __syncthreads();
    #pragma unroll
    for (int k = 0; k < 4; ++k){
      int pl = cl0 + 16*k;
      int pp = p0 + pl;
      if (pp < P){
        float4 o = make_float4(t[4*q+0][pl], t[4*q+1][pl],
                               t[4*q+2][pl], t[4*q+3][pl]);
        *(float4*)(dst + (size_t)pp*256 + c0 + 4*q) = o;
      }
    }
    return;
  }
  // ---------------- NMS part ----------------
  int b = bid;
  int F = (int)fcnt_ws[b];
  const u64* Mb = M + (size_t)b*NC*MROW;
  int nch = (F + 63) >> 6;
  int lane = tid & 63, wv = tid >> 6;
  if (tid == 0){ s_kc = 0; s_done = (nch == 0) ? 1 : 0; }
  if (tid < 72) zbuf[tid] = 0ull;
  // stage chunk 0 (all 256 threads, direct)
  if (nch > 0){
    for (int e = tid; e < 64*72; e += 256){
      int rr = e / 72, wo = e - rr*72;
      int r2 = rr; if (r2 > NC-1) r2 = NC-1;
      buf[0][e] = Mb[(size_t)r2*MROW + wo];
    }
  }
  // waves 1-3: load chunk 1 into registers (depth-2 pipeline primer)
  u64 rg[24];
  if (wv > 0 && nch > 1){
    #pragma unroll
    for (int k = 0; k < 24; ++k){
      int e = (tid - 64) + k*192;
      int rr = e/72, wo = e - rr*72;
      int r2 = 64 + rr; if (r2 > NC-1) r2 = NC-1;
      rg[k] = Mb[(size_t)r2*MROW + wo];
    }
  }
  __syncthreads();
  u64 sup0 = 0, sup1 = 0;
  int kc = 0;
  for (int c = 0; c < nch; ++c){
    int cb = c & 1;
    if (wv > 0){
      // write chunk c+1 (in regs) to the other buffer; load chunk c+2
      if (c + 1 < nch){
        #pragma unroll
        for (int k = 0; k < 24; ++k){
          int e = (tid - 64) + k*192;
          buf[cb^1][e] = rg[k];
        }
      }
      if (c + 2 < nch){
        int base2 = (c + 2) << 6;
        #pragma unroll
        for (int k = 0; k < 24; ++k){
          int e = (tid - 64) + k*192;
          int rr = e/72, wo = e - rr*72;
          int r2 = base2 + rr; if (r2 > NC-1) r2 = NC-1;
          rg[k] = Mb[(size_t)r2*MROW + wo];
        }
      }
    } else if (kc < 1000){
      int base = c << 6;
      int cnt = F - base; if (cnt > 64) cnt = 64;
      u64 supw = (c < 64) ? readlane64(sup0, c) : readlane64(sup1, c - 64);
      u64 alive = ~supw;
      if (cnt < 64) alive &= ((1ull << cnt) - 1ull);
      u64 wrow = buf[cb][lane*72 + c];   // my row's word for this chunk == my column (symmetric IoU)
      u64 below = lane ? (~0ull >> (64 - lane)) : 0ull;
      u64 colb = wrow & below;           // earlier in-chunk boxes that suppress me
      bool myal = ((alive >> lane) & 1ull) != 0ull;
      u64 kept = __ballot(myal);
      // Jacobi iteration to the unique fixed point == greedy NMS within chunk
      #pragma unroll 1
      for (int it = 0; it < 64; ++it){
        bool kj = myal && ((kept & colb) == 0ull);
        u64 nk = __ballot(kj);
        if (nk == kept) break;
        kept = nk;
      }
      int cnt_k = __popcll(kept);
      int rank  = __popcll(kept & below);
      int budget = 1000 - kc;
      bool sel = ((kept >> lane) & 1ull) && (rank < budget);
      if (sel) ki[kc + rank] = base + lane;
      if (cnt_k >= budget){
        if (lane == 0){ s_done = 1; s_kc = 1000; }
      } else {
        kc += cnt_k;
        // batched OR of kept rows from LDS (16 at a time, zero-row padded)
        u64 t2 = kept;
        while (t2){
          const u64 *q0,*q1,*q2,*q3,*q4,*q5,*q6,*q7;
          const u64 *q8,*q9,*q10,*q11,*q12,*q13,*q14,*q15;
          GETQ2(q0) GETQ2(q1) GETQ2(q2) GETQ2(q3)
          GETQ2(q4) GETQ2(q5) GETQ2(q6) GETQ2(q7)
          GETQ2(q8) GETQ2(q9) GETQ2(q10) GETQ2(q11)
          GETQ2(q12) GETQ2(q13) GETQ2(q14) GETQ2(q15)
          u64 a0=q0[lane],a1=q1[lane],a2=q2[lane],a3=q3[lane];
          u64 a4=q4[lane],a5=q5[lane],a6=q6[lane],a7=q7[lane];
          u64 a8=q8[lane],a9=q9[lane],a10=q10[lane],a11=q11[lane];
          u64 a12=q12[lane],a13=q13[lane],a14=q14[lane],a15=q15[lane];
          sup0 |= (((a0|a1)|(a2|a3))|((a4|a5)|(a6|a7)))
                | (((a8|a9)|(a10|a11))|((a12|a13)|(a14|a15)));
          if (lane < 7){
            u64 b0=q0[64+lane],b1=q1[64+lane],b2=q2[64+lane],b3=q3[64+lane];
            u64 b4=q4[64+lane],b5=q5[64+lane],b6=q6[64+lane],b7=q7[64+lane];
            u64 b8=q8[64+lane],b9=q9[64+lane],b10=q10[64+lane],b11=q11[64+lane];
            u64 b12=q12[64+lane],b13=q13[64+lane],b14=q14[64+lane],b15=q15[64+lane];
            sup1 |= (((b0|b1)|(b2|b3))|((b4|b5)|(b6|b7)))
                  | (((b8|b9)|(b10|b11))|((b12|b13)|(b14|b15)));
          }
        }
        if (lane == 0) s_kc = kc;
      }
    }
    __syncthreads();
    if (s_done) break;      // uniform LDS value across the block
  }
  __syncthreads();
  int kcf = s_kc;
  const float* sb = sorted_box + (size_t)b*NC*4;
  float* pb = props + (size_t)b*4000;
  float4 p0v = ((const float4*)pos0box)[b];
  float pv[4] = {p0v.x, p0v.y, p0v.z, p0v.w};
  for (int idx = tid; idx < 4000; idx += 256){
    int k4 = idx >> 2, comp = idx & 3;
    float v = (k4 < kcf) ? sb[(size_t)ki[k4]*4 + comp] : pv[comp];
    pb[idx] = v;
  }
}

// ---------------- 7a. ROI Align, NHWC path -------------------------------
// Channel-split two-pass (128 ch each): lane quad q=tid&31, pixel slot
// s=tid>>5. obuf[49][132] = 25.9KB -> 4 blocks/CU; epilogue per pass is a
// contiguous coalesced 25KB region. Bit-identical output.
__global__ __launch_bounds__(256, 4) void k_roi_nhwc(const float* nhwc, const float* props,
                                                     float* out){
#pragma clang fp contract(off)
  int r = blockIdx.x;
  int b = r / 1000;
  int tid = threadIdx.x;
  int q = tid & 31;          // channel quad within 128-ch half
  int s = tid >> 5;          // pixel slot 0..7
  __shared__ int   s_o0[196], s_o1[196], s_o2[196], s_o3[196];
  __shared__ float s_a0[196], s_a1[196], s_a2[196], s_a3[196], s_m[196];
  __shared__ float obuf[49*132];     // 25,872 B ; row = 33 float4 (16B-aligned stores)
  float bx0 = props[(size_t)r*4+0], by0 = props[(size_t)r*4+1];
  float bx1 = props[(size_t)r*4+2], by1 = props[(size_t)r*4+3];
  float area = (bx1-bx0)*(by1-by0);
  float v = 4.0f + log2f(sqrtf(area)/224.0f + 1e-6f);
  float fl = floorf(v);
  fl = fminf(fmaxf(fl, 2.0f), 5.0f);
  int li = (int)fl - 2;
  int H = (li==0)?200:(li==1)?100:(li==2)?50:25;
  u32 loff = (li==0)?0u:(li==1)?NHWC_L1:(li==2)?NHWC_L2:NHWC_L3;
  float scale = (li==0)?0.25f:(li==1)?0.125f:(li==2)?0.0625f:0.03125f;
  float x1 = bx0*scale, y1 = by0*scale, x2 = bx1*scale, y2 = by1*scale;
  float rw = fmaxf(x2-x1, 1.0f), rh = fmaxf(y2-y1, 1.0f);
  if (tid < 196){
    int syi = tid / 14, sxi = tid - syi*14;
    float ty = ((float)syi + 0.5f)/14.0f;
    float yv = y1 + rh*ty;
    float fy = (yv >= -1.0f && yv <= (float)H) ? 1.0f : 0.0f;
    float yc = fminf(fmaxf(yv,0.0f),(float)(H-1));
    int iy0 = (int)floorf(yc);
    int iy1 = min(iy0+1,H-1);
    float ly = yc-(float)iy0;
    float tx = ((float)sxi + 0.5f)/14.0f;
    float xv = x1 + rw*tx;
    float fx = (xv >= -1.0f && xv <= (float)H) ? 1.0f : 0.0f;
    float xc = fminf(fmaxf(xv,0.0f),(float)(H-1));
    int ix0 = (int)floorf(xc);
    int ix1 = min(ix0+1,H-1);
    float lx = xc-(float)ix0;
    s_o0[tid] = (iy0*H + ix0)*64;    // offsets in float4 units
    s_o1[tid] = (iy0*H + ix1)*64;
    s_o2[tid] = (iy1*H + ix0)*64;
    s_o3[tid] = (iy1*H + ix1)*64;
    s_a0[tid] = (1.f-ly)*(1.f-lx);
    s_a1[tid] = (1.f-ly)*lx;
    s_a2[tid] = ly*(1.f-lx);
    s_a3[tid] = ly*lx;
    s_m[tid]  = fy*fx;
  }
  __syncthreads();
  const float4* src4 = (const float4*)(nhwc + (size_t)b*NHWC_BS + loff);
  float4* obuf4 = (float4*)obuf;
  float* orow = out + (size_t)r*12544;
  #pragma unroll 1
  for (int h = 0; h < 2; ++h){
    int qh = h*32 + q;
    for (int p = s; p < 49; p += 8){
      int py = p/7, px = p - py*7;
      float accx = 0.f, accy = 0.f, accz = 0.f, accw = 0.f;
      #pragma unroll
      for (int iy = 0; iy < 2; ++iy){
        #pragma unroll
        for (int ix = 0; ix < 2; ++ix){
          int sp = (py*2+iy)*14 + (px*2+ix);
          int o00 = s_o0[sp], o01 = s_o1[sp], o10 = s_o2[sp], o11 = s_o3[sp];
          float a00 = s_a0[sp], a01 = s_a1[sp], a10 = s_a2[sp], a11 = s_a3[sp];
          float m = s_m[sp];
          float4 v00 = src4[o00 + qh];
          float4 v01 = src4[o01 + qh];
          float4 v10 = src4[o10 + qh];
          float4 v11 = src4[o11 + qh];
          accx += (a00*v00.x + a01*v01.x + a10*v10.x + a11*v11.x)*m;
          accy += (a00*v00.y + a01*v01.y + a10*v10.y + a11*v11.y)*m;
          accz += (a00*v00.z + a01*v01.z + a10*v10.z + a11*v11.z)*m;
          accw += (a00*v00.w + a01*v01.w + a10*v10.w + a11*v11.w)*m;
        }
      }
      obuf4[p*33 + q] = make_float4(accx*0.25f, accy*0.25f, accz*0.25f, accw*0.25f);
    }
    __syncthreads();
    // contiguous coalesced epilogue: channels [h*128,(h+1)*128) x 49 pixels
    for (int o = tid; o < 6272; o += 256){
      int c = o/49, p = o - c*49;
      orow[h*6272 + o] = obuf[p*132 + c];
    }
    __syncthreads();       // obuf reused next pass
  }
}

// ---------------- 7b. ROI Align, direct-NCHW fallback ----------------------
__global__ __launch_bounds__(256) void k_roi(const float* f0, const float* f1,
                                             const float* f2, const float* f3,
                                             const float* props, float* out){
#pragma clang fp contract(off)
  int r = blockIdx.x;
  int b = r / 1000;
  int tid = threadIdx.x;
  __shared__ float s_ly[14], s_lx[14], s_ym[14], s_xm[14];
  __shared__ int   s_y0[14], s_y1[14], s_x0[14], s_x1[14];
  float bx0 = props[(size_t)r*4+0], by0 = props[(size_t)r*4+1];
  float bx1 = props[(size_t)r*4+2], by1 = props[(size_t)r*4+3];
  float area = (bx1-bx0)*(by1-by0);
  float v = 4.0f + log2f(sqrtf(area)/224.0f + 1e-6f);
  float fl = floorf(v);
  fl = fminf(fmaxf(fl, 2.0f), 5.0f);
  int li = (int)fl - 2;
  const float* fptr = (li==0)?f0:(li==1)?f1:(li==2)?f2:f3;
  int H = (li==0)?200:(li==1)?100:(li==2)?50:25;
  float scale = (li==0)?0.25f:(li==1)?0.125f:(li==2)?0.0625f:0.03125f;
  float x1 = bx0*scale, y1 = by0*scale, x2 = bx1*scale, y2 = by1*scale;
  float rw = fmaxf(x2-x1, 1.0f), rh = fmaxf(y2-y1, 1.0f);
  if (tid < 14){
    float t = ((float)tid + 0.5f)/14.0f;
    float yv = y1 + rh*t;
    s_ym[tid] = (yv >= -1.0f && yv <= (float)H) ? 1.0f : 0.0f;
    float yc = fminf(fmaxf(yv,0.0f),(float)(H-1));
    int iy0 = (int)floorf(yc);
    s_y0[tid]=iy0; s_y1[tid]=min(iy0+1,H-1); s_ly[tid]=yc-(float)iy0;
    float xv = x1 + rw*t;
    s_xm[tid] = (xv >= -1.0f && xv <= (float)H) ? 1.0f : 0.0f;
    float xc = fminf(fmaxf(xv,0.0f),(float)(H-1));
    int ix0 = (int)floorf(xc);
    s_x0[tid]=ix0; s_x1[tid]=min(ix0+1,H-1); s_lx[tid]=xc-(float)ix0;
  }
  __syncthreads();
  size_t plane = (size_t)H*H;
  const float* fb = fptr + (size_t)b*256*plane;
  float* orow = out + (size_t)r*12544;
  for (int o=tid; o<12544; o+=256){
    int c = o/49;
    int p = o - c*49;
    int py = p/7, px = p - py*7;
    const float* fc = fb + (size_t)c*plane;
    float sum = 0.f;
    for (int iy=0; iy<2; iy++){
      int syi = py*2+iy;
      int yy0 = s_y0[syi], yy1 = s_y1[syi];
      float ly = s_ly[syi], fy = s_ym[syi];
      for (int ix=0; ix<2; ix++){
        int sxi = px*2+ix;
        int xx0 = s_x0[sxi], xx1 = s_x1[sxi];
        float lx = s_lx[sxi], fx = s_xm[sxi];
        float v00 = fc[yy0*H+xx0], v01 = fc[yy0*H+xx1];
        float v10 = fc[yy1*H+xx0], v11 = fc[yy1*H+xx1];
        float val = ((1.f-ly)*(1.f-lx)*v00 + (1.f-ly)*lx*v01
                   + ly*(1.f-lx)*v10 + ly*lx*v11) * (fy*fx);
        sum += val;
      }
    }
    orow[o] = sum*0.25f;
  }
}

extern "C" void kernel_launch(void* const* d_in, const int* in_sizes, int n_in,
                              void* d_out, int out_size, void* d_ws, size_t ws_size,
                              hipStream_t stream) {
  int B = in_sizes[0] / (3*800*800);
  PtrArgs pa;
  bool interleaved = (n_in >= 7) && (in_sizes[6] == 4*in_sizes[5]);
  for (int i=0;i<5;i++){
    if (interleaved){
      pa.obj[i] = (const float*)d_in[5+2*i];
      pa.dl[i]  = (const float*)d_in[6+2*i];
    } else {
      pa.obj[i] = (const float*)d_in[5+i];
      pa.dl[i]  = (const float*)d_in[10+i];
    }
  }

  // ---- small scratch in the TAIL of d_out (overwritten last by ROI) ----
  auto align256 = [](size_t x){ return (x + 255) & ~(size_t)255; };
  size_t sz_M      = align256(((size_t)B*NC + 1)*MROW*8);
  size_t sz_boxes  = align256((size_t)B*N_ALL*16);
  size_t sz_key    = align256((size_t)B*N_ALL*4);
  size_t sz_fkey   = align256((size_t)B*N_ALL*4);
  size_t sz_cand   = align256((size_t)B*NC*4);
  size_t sz_sbox   = align256((size_t)B*NC*16);
  size_t sz_soff   = align256((size_t)B*NC*16);
  size_t sz_fcnt   = align256((size_t)B*4);
  size_t sz_p0     = align256((size_t)B*16);
  size_t sz_ghist  = align256((size_t)B*5*HBINS*4);
  size_t sz_meta   = align256((size_t)B*5*8);
  size_t sz_wcnt   = align256((size_t)B*5*4);
  size_t sz_tcnt   = align256((size_t)B*5*4);
  size_t sz_tbuf   = align256((size_t)B*5*4096*8);
  size_t need = sz_M+sz_boxes+sz_key+sz_fkey+sz_cand+sz_sbox+sz_soff+sz_fcnt+sz_p0
              + sz_ghist+sz_meta+sz_wcnt+sz_tcnt+sz_tbuf;
  size_t outBytes = (size_t)out_size * 4;
  size_t start = (outBytes - need) & ~(size_t)255;
  char* w = (char*)d_out + start;
  auto alloc = [&](size_t bytes)->char*{ char* p = w; w += bytes; return p; };

  u64*  M          = (u64*) alloc(sz_M);
  float* boxes_all = (float*)alloc(sz_boxes);
  u32*  key_all    = (u32*) alloc(sz_key);
  u32*  fkey_all   = (u32*) alloc(sz_fkey);
  u32*  cand_g     = (u32*) alloc(sz_cand);
  float* sorted_box= (float*)alloc(sz_sbox);
  float* sorted_off= (float*)alloc(sz_soff);
  u32*  fcnt       = (u32*) alloc(sz_fcnt);
  float* pos0box   = (float*)alloc(sz_p0);
  u32*  ghist      = (u32*) alloc(sz_ghist);
  int2* meta       = (int2*)alloc(sz_meta);
  u32*  wcnt       = (u32*) alloc(sz_wcnt);
  u32*  tcnt       = (u32*) alloc(sz_tcnt);
  u64*  tbuf       = (u64*) alloc(sz_tbuf);

  float* props     = (float*)d_out;
  float* feats_out = (float*)d_out + (size_t)B*1000*4;

  int total = B*N_ALL;
  int nz = B*5*HBINS;
  k_zero<<<(nz+255)/256, 256, 0, stream>>>(ghist, wcnt, tcnt, B);
  k_decode<<<(total+255)/256, 256, 0, stream>>>(pa, B, boxes_all, key_all, fkey_all);
  k_hist<<<B*5*HCH, 256, 0, stream>>>(key_all, ghist, B);
  k_sel<<<B*5, 1024, 0, stream>>>(ghist, meta, B);
  k_emit<<<B*5*EMIT_S, 1024, 0, stream>>>(key_all, meta, cand_g, wcnt, tcnt, tbuf, B);
  k_fin<<<B*5, 1024, 0, stream>>>(meta, tcnt, tbuf, cand_g, B);
  k_rank<<<B*5, 1024, 0, stream>>>(cand_g, key_all, B);
  k_sortcand<<<B, 1024, 0, stream>>>(cand_g, fkey_all, boxes_all, sorted_box, sorted_off, fcnt, pos0box);
  k_iou<<<dim3(NC, B), 64, 0, stream>>>(sorted_off, M);

  size_t nhwcBytes = (size_t)B * NHWC_BS * 4;
  int doTr = (ws_size >= nhwcBytes) ? 1 : 0;
  float* nhwc = (float*)d_ws;
  int grid = B + (doTr ? B*3328 : 0);
  k_nms_tr<<<grid, 256, 0, stream>>>(sorted_box, M, fcnt, pos0box, props, B,
                                     (const float*)d_in[1], (const float*)d_in[2],
                                     (const float*)d_in[3], (const float*)d_in[4],
                                     nhwc, doTr);
  if (doTr){
    k_roi_nhwc<<<B*1000, 256, 0, stream>>>(nhwc, props, feats_out);
  } else {
    k_roi<<<B*1000, 256, 0, stream>>>((const float*)d_in[1], (const float*)d_in[2],
                                      (const float*)d_in[3], (const float*)d_in[4],
                                      props, feats_out);
  }
}